// Round 2
// baseline (264.765 us; speedup 1.0000x reference)
//
#include <hip/hip_runtime.h>
#include <math.h>

#define BB 64
#define NN 4096
#define DD 128
#define HH 256

// ---------------------------------------------------------------------------
// K1: scores[b,n] = sum_h relu(feats[b,n,:]·W1[:,h] + b1[h]) * W2[h]
// (b2 omitted: softmax over n is invariant to a constant shift)
// 64 nodes per block, 256 threads = 16 node-groups x 16 h-groups,
// 4x4 micro-tile per thread. feats tile XOR-swizzled in LDS.
// ---------------------------------------------------------------------------
__global__ __launch_bounds__(256) void k_scores(const float* __restrict__ feats,
                                                const float* __restrict__ W1,
                                                const float* __restrict__ b1,
                                                const float* __restrict__ W2,
                                                float* __restrict__ scores) {
    __shared__ float4 lds4[4096];       // 64 KiB total
    float4* fl = lds4;                  // [64 nodes][32 float4] feats tile (swizzled)
    float4* wl = lds4 + 2048;           // [128 d][16 float4] W1 chunk (64 h)
    float*  scratch = (float*)lds4;     // aliased after compute is done

    const int tid = threadIdx.x;
    const int ng  = tid & 15;           // node group: nodes ng, ng+16, ng+32, ng+48
    const int hg  = tid >> 4;           // h group: 4 h's per chunk
    const int blk = blockIdx.x;

    const float4* fg4 = (const float4*)feats;
    const float4* wg4 = (const float4*)W1;      // row stride = 64 float4
    const int fbase4 = blk * 2048;              // 64 nodes * 32 float4

    // stage feats tile, swizzled: row `node`, quad column c stored at c ^ (node&7)
    #pragma unroll
    for (int k = 0; k < 8; ++k) {
        int f = k * 256 + tid;                  // 0..2047
        int node = f >> 5, c = f & 31;
        fl[node * 32 + (c ^ (node & 7))] = fg4[fbase4 + f];
    }

    float sp0 = 0.f, sp1 = 0.f, sp2 = 0.f, sp3 = 0.f;
    const int sw = ng & 7;              // same for all 4 of this thread's nodes

    for (int hc = 0; hc < 4; ++hc) {
        __syncthreads();                // feats staged / previous wl use done
        // stage W1[:, hc*64 .. hc*64+63] -> wl[128][16 float4]
        #pragma unroll
        for (int k = 0; k < 8; ++k) {
            int f = k * 256 + tid;              // 0..2047
            int row = f >> 4, c4 = f & 15;
            wl[row * 16 + c4] = wg4[row * 64 + hc * 16 + c4];
        }
        __syncthreads();

        float4 acc0 = {0,0,0,0}, acc1 = {0,0,0,0}, acc2 = {0,0,0,0}, acc3 = {0,0,0,0};
        #pragma unroll 8
        for (int c = 0; c < 32; ++c) {
            const int cc = c ^ sw;
            float4 a0 = fl[(ng      ) * 32 + cc];
            float4 a1 = fl[(ng + 16) * 32 + cc];
            float4 a2 = fl[(ng + 32) * 32 + cc];
            float4 a3 = fl[(ng + 48) * 32 + cc];
            float4 w0 = wl[(c * 4 + 0) * 16 + hg];
            float4 w1 = wl[(c * 4 + 1) * 16 + hg];
            float4 w2 = wl[(c * 4 + 2) * 16 + hg];
            float4 w3 = wl[(c * 4 + 3) * 16 + hg];
#define MAC4(ACC, A)                                                              \
            ACC.x = fmaf(A.x, w0.x, fmaf(A.y, w1.x, fmaf(A.z, w2.x, fmaf(A.w, w3.x, ACC.x)))); \
            ACC.y = fmaf(A.x, w0.y, fmaf(A.y, w1.y, fmaf(A.z, w2.y, fmaf(A.w, w3.y, ACC.y)))); \
            ACC.z = fmaf(A.x, w0.z, fmaf(A.y, w1.z, fmaf(A.z, w2.z, fmaf(A.w, w3.z, ACC.z)))); \
            ACC.w = fmaf(A.x, w0.w, fmaf(A.y, w1.w, fmaf(A.z, w2.w, fmaf(A.w, w3.w, ACC.w))))
            MAC4(acc0, a0);
            MAC4(acc1, a1);
            MAC4(acc2, a2);
            MAC4(acc3, a3);
#undef MAC4
        }

        // fold relu(dot + b1) * W2 into score partials
        const int hbase = hc * 64 + hg * 4;
        const float4 bb = *(const float4*)&b1[hbase];
        const float4 ww = *(const float4*)&W2[hbase];
#define FOLD(SP, ACC)                                                    \
        SP += fmaxf(ACC.x + bb.x, 0.f) * ww.x;                           \
        SP += fmaxf(ACC.y + bb.y, 0.f) * ww.y;                           \
        SP += fmaxf(ACC.z + bb.z, 0.f) * ww.z;                           \
        SP += fmaxf(ACC.w + bb.w, 0.f) * ww.w
        FOLD(sp0, acc0);
        FOLD(sp1, acc1);
        FOLD(sp2, acc2);
        FOLD(sp3, acc3);
#undef FOLD
    }

    __syncthreads();                    // feats tile no longer needed -> scratch
    const int lane = tid & 63;
    const int wv   = tid >> 6;
    float v;
#define REDUCE_STORE(SP, I)                                              \
    v = SP;                                                              \
    v += __shfl_xor(v, 16);                                              \
    v += __shfl_xor(v, 32);                                              \
    if (lane < 16) scratch[wv * 64 + lane + 16 * (I)] = v
    REDUCE_STORE(sp0, 0);
    REDUCE_STORE(sp1, 1);
    REDUCE_STORE(sp2, 2);
    REDUCE_STORE(sp3, 3);
#undef REDUCE_STORE
    __syncthreads();
    if (tid < 64) {
        float s = scratch[tid] + scratch[64 + tid] + scratch[128 + tid] + scratch[192 + tid];
        scores[blk * 64 + tid] = s;
    }
}

// ---------------------------------------------------------------------------
// K2: per-batch max and 1/sum(exp) over N scores
// ---------------------------------------------------------------------------
__global__ __launch_bounds__(256) void k_stats(const float* __restrict__ scores,
                                               float* __restrict__ mz) {
    const int b = blockIdx.x, tid = threadIdx.x;
    float s[16];
    #pragma unroll
    for (int k = 0; k < 16; ++k) s[k] = scores[b * NN + k * 256 + tid];

    float m = -1e30f;
    #pragma unroll
    for (int k = 0; k < 16; ++k) m = fmaxf(m, s[k]);
    #pragma unroll
    for (int o = 1; o < 64; o <<= 1) m = fmaxf(m, __shfl_xor(m, o));

    __shared__ float redm[4], redz[4];
    const int wv = tid >> 6, lane = tid & 63;
    if (lane == 0) redm[wv] = m;
    __syncthreads();
    m = fmaxf(fmaxf(redm[0], redm[1]), fmaxf(redm[2], redm[3]));

    float z = 0.f;
    #pragma unroll
    for (int k = 0; k < 16; ++k) z += expf(s[k] - m);
    #pragma unroll
    for (int o = 1; o < 64; o <<= 1) z += __shfl_xor(z, o);
    if (lane == 0) redz[wv] = z;
    __syncthreads();
    if (tid == 0) {
        z = redz[0] + redz[1] + redz[2] + redz[3];
        mz[b * 2]     = m;
        mz[b * 2 + 1] = 1.0f / z;
    }
}

// ---------------------------------------------------------------------------
// K3: partial weighted sums. block = (b, chunk of 256 nodes).
// ---------------------------------------------------------------------------
__global__ __launch_bounds__(256) void k_wsum(const float* __restrict__ feats,
                                              const float* __restrict__ scores,
                                              const float* __restrict__ mz,
                                              float* __restrict__ partials) {
    const int blk = blockIdx.x;
    const int b = blk >> 4, ch = blk & 15;
    const int tid = threadIdx.x;
    const int n0 = ch * 256;

    __shared__ float  wsm[256];
    __shared__ float4 accl[256];

    const float m  = mz[b * 2];
    const float iz = mz[b * 2 + 1];
    wsm[tid] = expf(scores[b * NN + n0 + tid] - m) * iz;
    __syncthreads();

    const int d4 = tid & 31;            // float4 column
    const int part = tid >> 5;          // 8 node-subchunks of 32
    const float4* fg4 = (const float4*)feats;
    const int base4 = (b * NN + n0 + part * 32) * 32;   // row stride = 32 float4

    float4 acc = {0,0,0,0};
    #pragma unroll 8
    for (int k = 0; k < 32; ++k) {
        const float w = wsm[part * 32 + k];
        const float4 f = fg4[base4 + k * 32 + d4];
        acc.x = fmaf(w, f.x, acc.x);
        acc.y = fmaf(w, f.y, acc.y);
        acc.z = fmaf(w, f.z, acc.z);
        acc.w = fmaf(w, f.w, acc.w);
    }
    accl[tid] = acc;
    __syncthreads();
    if (tid < 32) {
        float4 s = accl[tid];
        #pragma unroll
        for (int p = 1; p < 8; ++p) {
            float4 t = accl[p * 32 + tid];
            s.x += t.x; s.y += t.y; s.z += t.z; s.w += t.w;
        }
        ((float4*)partials)[blk * 32 + tid] = s;
    }
}

// ---------------------------------------------------------------------------
// K4: fold 16 chunk partials -> out[b,d]
// ---------------------------------------------------------------------------
__global__ __launch_bounds__(256) void k_final(const float* __restrict__ partials,
                                               float* __restrict__ out) {
    const int t = blockIdx.x * 256 + threadIdx.x;   // 0..8191
    const int b = t >> 7, d = t & 127;
    float s = 0.f;
    #pragma unroll
    for (int ch = 0; ch < 16; ++ch) s += partials[((b * 16 + ch) << 7) + d];
    out[t] = s;
}

extern "C" void kernel_launch(void* const* d_in, const int* in_sizes, int n_in,
                              void* d_out, int out_size, void* d_ws, size_t ws_size,
                              hipStream_t stream) {
    const float* feats = (const float*)d_in[0];
    const float* W1    = (const float*)d_in[1];
    const float* b1    = (const float*)d_in[2];
    const float* W2    = (const float*)d_in[3];
    // d_in[4] = b2: constant shift before softmax -> no effect on output.
    float* out = (float*)d_out;

    float* ws       = (float*)d_ws;
    float* scores   = ws;                       // B*N          = 262144 floats
    float* mz       = ws + 262144;              // 2*B          = 128 floats
    float* partials = ws + 262144 + 128;        // B*16*D       = 131072 floats

    hipLaunchKernelGGL(k_scores, dim3(BB * NN / 64), dim3(256), 0, stream,
                       feats, W1, b1, W2, scores);
    hipLaunchKernelGGL(k_stats, dim3(BB), dim3(256), 0, stream, scores, mz);
    hipLaunchKernelGGL(k_wsum, dim3(BB * 16), dim3(256), 0, stream,
                       feats, scores, mz, partials);
    hipLaunchKernelGGL(k_final, dim3(32), dim3(256), 0, stream, partials, out);
}

// Round 4
// 93.952 us; speedup vs baseline: 2.8181x; 2.8181x over previous
//
#include <hip/hip_runtime.h>
#include <math.h>

#define BB 64
#define NN 4096
#define DD 128
#define HH 256
#define MB 128                  // rows per k_scores block

typedef __attribute__((ext_vector_type(8))) short bf16x8;
typedef __attribute__((ext_vector_type(4))) float f32x4;

static __device__ __forceinline__ unsigned short f2bf(float x) {
    unsigned int b = __float_as_uint(x);
    unsigned int r = (b + 0x7FFFu + ((b >> 16) & 1u)) >> 16;
    return (unsigned short)r;
}
static __device__ __forceinline__ float bf2f(unsigned short u) {
    return __uint_as_float(((unsigned int)u) << 16);
}
static __device__ __forceinline__ void gload_lds16(const void* g, void* l) {
    __builtin_amdgcn_global_load_lds(
        (const __attribute__((address_space(1))) unsigned int*)g,
        (__attribute__((address_space(3))) unsigned int*)l, 16, 0, 0);
}

// ---------------------------------------------------------------------------
// k_prep: W1 [128][256] fp32 -> ws: per 16-col chunk, transposed bf16 hi/lo,
// XOR-swizzled exactly as it will sit in LDS (linear global_load_lds copy).
// chunk region = 8192 B: [hi 4096 | lo 4096]; elem (cl,k) at
// ((cl<<8)+(k<<1)) ^ ((cl&7)<<4).
// ---------------------------------------------------------------------------
__global__ __launch_bounds__(256) void k_prep(const float* __restrict__ W1,
                                              char* __restrict__ Bws) {
    const int k = blockIdx.x;       // 0..127
    const int c = threadIdx.x;      // 0..255
    float x = W1[k * HH + c];
    unsigned short hi = f2bf(x);
    unsigned short lo = f2bf(x - bf2f(hi));
    const int chunk = c >> 4, cl = c & 15;
    const int off = ((cl << 8) + (k << 1)) ^ ((cl & 7) << 4);
    *(unsigned short*)(Bws + chunk * 8192 + off) = hi;
    *(unsigned short*)(Bws + chunk * 8192 + 4096 + off) = lo;
}

// ---------------------------------------------------------------------------
// k_scores: scores[b,n] = sum_h relu(feats[n,:]·W1[:,h] + b1[h]) * W2[h]
// bf16 hi/lo split MFMA: acc = Ahi·Bhi + Ahi·Blo + Alo·Bhi  (fp32-grade).
// 128 rows/block, 4 waves x 2 row-tiles(16x) x 16 col-tiles, K=128.
// ---------------------------------------------------------------------------
__global__ __launch_bounds__(256, 2) void k_scores(const float* __restrict__ feats,
                                                   const char* __restrict__ Bws,
                                                   const float* __restrict__ b1,
                                                   const float* __restrict__ W2,
                                                   float* __restrict__ scores) {
    __shared__ char lds[81920];
    char* Ahi = lds;                // [128 rows][128 k] bf16 swizzled, 32 KiB
    char* Alo = lds + 32768;        // 32 KiB
    char* Bb  = lds + 65536;        // 2 x (hi 4 KiB | lo 4 KiB)

    const int tid  = threadIdx.x;
    const int lane = tid & 63;
    const int wv   = tid >> 6;
    const int blk  = blockIdx.x;

    // ---- stage A: 128x128 fp32 -> bf16 hi/lo, swizzled ds_write_b64
    // 128 rows x 128 k = 4096 float4 -> 16 iterations of 256 threads.
    // (round-3 bug: 8 iterations staged only rows 0..63; waves 2,3 then
    //  consumed uninitialized LDS -> inf scores -> NaN softmax)
    const float4* fg4 = (const float4*)feats;
    const int fbase = blk * (MB * DD / 4);          // 4096 float4 per block
    #pragma unroll
    for (int it = 0; it < 16; ++it) {
        int f = it * 256 + tid;                     // 0..4095
        int row = f >> 5, c4 = f & 31;              // k = c4*4
        float4 v = fg4[fbase + f];
        unsigned short h0 = f2bf(v.x), h1 = f2bf(v.y), h2 = f2bf(v.z), h3 = f2bf(v.w);
        unsigned short l0 = f2bf(v.x - bf2f(h0)), l1 = f2bf(v.y - bf2f(h1));
        unsigned short l2 = f2bf(v.z - bf2f(h2)), l3 = f2bf(v.w - bf2f(h3));
        uint2 hp, lp;
        hp.x = (unsigned)h0 | ((unsigned)h1 << 16);
        hp.y = (unsigned)h2 | ((unsigned)h3 << 16);
        lp.x = (unsigned)l0 | ((unsigned)l1 << 16);
        lp.y = (unsigned)l2 | ((unsigned)l3 << 16);
        int off = ((row << 8) + (c4 << 3)) ^ ((row & 7) << 4);
        *(uint2*)(Ahi + off) = hp;
        *(uint2*)(Alo + off) = lp;
    }

    // ---- stage B chunk 0 -> buf 0 (linear copy; data pre-swizzled in ws)
    {
        const char* gsrc = Bws;
        gload_lds16(gsrc +        wv * 1024 + lane * 16, Bb +        wv * 1024);
        gload_lds16(gsrc + 4096 + wv * 1024 + lane * 16, Bb + 4096 + wv * 1024);
    }
    __syncthreads();

    // ---- A fragments for this wave's 2 row-tiles (held in VGPRs throughout)
    const int r0 = wv * 32;
    const int kq = (lane >> 4) << 4;                // k-part byte offset
    bf16x8 ah[2][4], al[2][4];
    #pragma unroll
    for (int t = 0; t < 2; ++t) {
        int r = r0 + t * 16 + (lane & 15);
        int rb = r << 8, swz = (r & 7) << 4;
        #pragma unroll
        for (int kk = 0; kk < 4; ++kk) {
            int off = (rb + (kk << 6) + kq) ^ swz;
            ah[t][kk] = *(const bf16x8*)(Ahi + off);
            al[t][kk] = *(const bf16x8*)(Alo + off);
        }
    }

    float sp[2][4] = {{0, 0, 0, 0}, {0, 0, 0, 0}};
    const int cl = lane & 15;
    const int brow = cl << 8;
    const int bswz = (cl & 7) << 4;

    for (int chunk = 0; chunk < 16; ++chunk) {
        // prefetch next chunk into the other buffer; latency hides under MFMA,
        // drained by the end-of-chunk __syncthreads (vmcnt(0) before barrier).
        if (chunk < 15) {
            const char* gsrc = Bws + (chunk + 1) * 8192;
            char* dst = Bb + ((chunk + 1) & 1) * 8192;
            gload_lds16(gsrc +        wv * 1024 + lane * 16, dst +        wv * 1024);
            gload_lds16(gsrc + 4096 + wv * 1024 + lane * 16, dst + 4096 + wv * 1024);
        }
        const char* nb = Bb + (chunk & 1) * 8192;
        f32x4 acc0 = {0, 0, 0, 0}, acc1 = {0, 0, 0, 0};
        #pragma unroll
        for (int kk = 0; kk < 4; ++kk) {
            int off = (brow + (kk << 6) + kq) ^ bswz;
            bf16x8 bh = *(const bf16x8*)(nb + off);
            bf16x8 bl = *(const bf16x8*)(nb + 4096 + off);
            acc0 = __builtin_amdgcn_mfma_f32_16x16x32_bf16(ah[0][kk], bh, acc0, 0, 0, 0);
            acc1 = __builtin_amdgcn_mfma_f32_16x16x32_bf16(ah[1][kk], bh, acc1, 0, 0, 0);
            acc0 = __builtin_amdgcn_mfma_f32_16x16x32_bf16(ah[0][kk], bl, acc0, 0, 0, 0);
            acc1 = __builtin_amdgcn_mfma_f32_16x16x32_bf16(ah[1][kk], bl, acc1, 0, 0, 0);
            acc0 = __builtin_amdgcn_mfma_f32_16x16x32_bf16(al[0][kk], bh, acc0, 0, 0, 0);
            acc1 = __builtin_amdgcn_mfma_f32_16x16x32_bf16(al[1][kk], bh, acc1, 0, 0, 0);
        }
        // fold relu + W2; D layout: col = lane&15, row = (lane>>4)*4 + j
        int c = (chunk << 4) + cl;
        float bbv = b1[c], ww = W2[c];
        #pragma unroll
        for (int j = 0; j < 4; ++j) {
            sp[0][j] += fmaxf(acc0[j] + bbv, 0.f) * ww;
            sp[1][j] += fmaxf(acc1[j] + bbv, 0.f) * ww;
        }
        __syncthreads();
    }

    // reduce over the 16 lanes sharing a row-quarter (cols 0..15 mod 16)
    #pragma unroll
    for (int m = 1; m < 16; m <<= 1) {
        #pragma unroll
        for (int t = 0; t < 2; ++t)
            #pragma unroll
            for (int j = 0; j < 4; ++j)
                sp[t][j] += __shfl_xor(sp[t][j], m);
    }
    if ((lane & 15) == 0) {
        const int q = lane >> 4;
        float* so = scores + blk * MB + wv * 32;
        #pragma unroll
        for (int t = 0; t < 2; ++t)
            #pragma unroll
            for (int j = 0; j < 4; ++j)
                so[t * 16 + q * 4 + j] = sp[t][j];
    }
}

// ---------------------------------------------------------------------------
// K2: per-batch max and 1/sum(exp) over N scores
// ---------------------------------------------------------------------------
__global__ __launch_bounds__(256) void k_stats(const float* __restrict__ scores,
                                               float* __restrict__ mz) {
    const int b = blockIdx.x, tid = threadIdx.x;
    float s[16];
    #pragma unroll
    for (int k = 0; k < 16; ++k) s[k] = scores[b * NN + k * 256 + tid];

    float m = -1e30f;
    #pragma unroll
    for (int k = 0; k < 16; ++k) m = fmaxf(m, s[k]);
    #pragma unroll
    for (int o = 1; o < 64; o <<= 1) m = fmaxf(m, __shfl_xor(m, o));

    __shared__ float redm[4], redz[4];
    const int wv = tid >> 6, lane = tid & 63;
    if (lane == 0) redm[wv] = m;
    __syncthreads();
    m = fmaxf(fmaxf(redm[0], redm[1]), fmaxf(redm[2], redm[3]));

    float z = 0.f;
    #pragma unroll
    for (int k = 0; k < 16; ++k) z += expf(s[k] - m);
    #pragma unroll
    for (int o = 1; o < 64; o <<= 1) z += __shfl_xor(z, o);
    if (lane == 0) redz[wv] = z;
    __syncthreads();
    if (tid == 0) {
        z = redz[0] + redz[1] + redz[2] + redz[3];
        mz[b * 2]     = m;
        mz[b * 2 + 1] = 1.0f / z;
    }
}

// ---------------------------------------------------------------------------
// K3: partial weighted sums. block = (b, chunk of 256 nodes).
// ---------------------------------------------------------------------------
__global__ __launch_bounds__(256) void k_wsum(const float* __restrict__ feats,
                                              const float* __restrict__ scores,
                                              const float* __restrict__ mz,
                                              float* __restrict__ partials) {
    const int blk = blockIdx.x;
    const int b = blk >> 4, ch = blk & 15;
    const int tid = threadIdx.x;
    const int n0 = ch * 256;

    __shared__ float  wsm[256];
    __shared__ float4 accl[256];

    const float m  = mz[b * 2];
    const float iz = mz[b * 2 + 1];
    wsm[tid] = expf(scores[b * NN + n0 + tid] - m) * iz;
    __syncthreads();

    const int d4 = tid & 31;
    const int part = tid >> 5;
    const float4* fg4 = (const float4*)feats;
    const int base4 = (b * NN + n0 + part * 32) * 32;

    float4 acc = {0, 0, 0, 0};
    #pragma unroll 8
    for (int k = 0; k < 32; ++k) {
        const float w = wsm[part * 32 + k];
        const float4 f = fg4[base4 + k * 32 + d4];
        acc.x = fmaf(w, f.x, acc.x);
        acc.y = fmaf(w, f.y, acc.y);
        acc.z = fmaf(w, f.z, acc.z);
        acc.w = fmaf(w, f.w, acc.w);
    }
    accl[tid] = acc;
    __syncthreads();
    if (tid < 32) {
        float4 s = accl[tid];
        #pragma unroll
        for (int p = 1; p < 8; ++p) {
            float4 t = accl[p * 32 + tid];
            s.x += t.x; s.y += t.y; s.z += t.z; s.w += t.w;
        }
        ((float4*)partials)[blk * 32 + tid] = s;
    }
}

// ---------------------------------------------------------------------------
// K4: fold 16 chunk partials -> out[b,d]
// ---------------------------------------------------------------------------
__global__ __launch_bounds__(256) void k_final(const float* __restrict__ partials,
                                               float* __restrict__ out) {
    const int t = blockIdx.x * 256 + threadIdx.x;   // 0..8191
    const int b = t >> 7, d = t & 127;
    float s = 0.f;
    #pragma unroll
    for (int ch = 0; ch < 16; ++ch) s += partials[((b * 16 + ch) << 7) + d];
    out[t] = s;
}

extern "C" void kernel_launch(void* const* d_in, const int* in_sizes, int n_in,
                              void* d_out, int out_size, void* d_ws, size_t ws_size,
                              hipStream_t stream) {
    const float* feats = (const float*)d_in[0];
    const float* W1    = (const float*)d_in[1];
    const float* b1    = (const float*)d_in[2];
    const float* W2    = (const float*)d_in[3];
    // d_in[4] = b2: constant shift before softmax -> no effect on output.
    float* out = (float*)d_out;

    float* ws       = (float*)d_ws;
    float* scores   = ws;                       // 262144 floats
    float* mz       = ws + 262144;              // 128 floats
    float* partials = ws + 262144 + 128;        // 131072 floats
    char*  Bws      = (char*)d_ws + 1573376;    // 128 KiB: W1t hi/lo, swizzled

    hipLaunchKernelGGL(k_prep, dim3(DD), dim3(HH), 0, stream, W1, Bws);
    hipLaunchKernelGGL(k_scores, dim3(BB * NN / MB), dim3(256), 0, stream,
                       feats, Bws, b1, W2, scores);
    hipLaunchKernelGGL(k_stats, dim3(BB), dim3(256), 0, stream, scores, mz);
    hipLaunchKernelGGL(k_wsum, dim3(BB * 16), dim3(256), 0, stream,
                       feats, scores, mz, partials);
    hipLaunchKernelGGL(k_final, dim3(32), dim3(256), 0, stream, partials, out);
}

// Round 5
// 69.624 us; speedup vs baseline: 3.8028x; 1.3494x over previous
//
#include <hip/hip_runtime.h>
#include <math.h>

#define BB 64
#define NN 4096
#define DD 128
#define HH 256
#define MB 256                  // rows per k_scores block (4 waves x 4 tiles of 16)

typedef __attribute__((ext_vector_type(8))) _Float16 f16x8;
typedef __attribute__((ext_vector_type(4))) float f32x4;

static __device__ __forceinline__ void gload_lds16(const void* g, void* l) {
    __builtin_amdgcn_global_load_lds(
        (const __attribute__((address_space(1))) unsigned int*)g,
        (__attribute__((address_space(3))) unsigned int*)l, 16, 0, 0);
}

// ---------------------------------------------------------------------------
// k_prep: W1 [128][256] fp32 -> Bws fp16, transposed per 16-col chunk,
// XOR-swizzled exactly as it will sit in LDS (linear global_load_lds copy).
// chunk region = 4096 B; elem (cl, k) at ((cl<<8)+(k<<1)) ^ ((cl&7)<<4).
// ---------------------------------------------------------------------------
__global__ __launch_bounds__(256) void k_prep(const float* __restrict__ W1,
                                              char* __restrict__ Bws) {
    const int k = blockIdx.x;       // 0..127
    const int c = threadIdx.x;      // 0..255
    const _Float16 h = (_Float16)W1[k * HH + c];
    const int chunk = c >> 4, cl = c & 15;
    const int off = ((cl << 8) + (k << 1)) ^ ((cl & 7) << 4);
    *(_Float16*)(Bws + chunk * 4096 + off) = h;
}

// ---------------------------------------------------------------------------
// k_scores: scores[b,n] = sum_h relu(feats[n,:]·W1[:,h] + b1[h]) * W2[h]
// fp16 MFMA (16x16x32_f16). W1t fp16 (64 KiB) staged ONCE in LDS; A loaded
// global->VGPR directly in fragment layout. No barriers in the main loop.
// ---------------------------------------------------------------------------
__global__ __launch_bounds__(256, 2) void k_scores(const float* __restrict__ feats,
                                                   const char* __restrict__ Bws,
                                                   const float* __restrict__ b1,
                                                   const float* __restrict__ W2,
                                                   float* __restrict__ scores) {
    __shared__ char Bl[65536];      // 16 chunks x 16 cols x 128 k, fp16 swizzled

    const int tid  = threadIdx.x;
    const int lane = tid & 63;
    const int wv   = tid >> 6;
    const int blk  = blockIdx.x;
    const int rl   = lane & 15;     // row within tile / B col within chunk
    const int q    = lane >> 4;     // k-quarter (8 elems)

    // ---- stage all of B: 64 KiB = 16 iters x 256 threads x 16 B (linear)
    #pragma unroll
    for (int it = 0; it < 16; ++it)
        gload_lds16(Bws + it * 4096 + tid * 16, Bl + it * 4096 + tid * 16);

    // ---- A fragments direct from global, converted fp32->fp16 in regs.
    // 16x16x32 A layout: lane holds row=rl, k = q*8 + kk*32 + e (e=0..7).
    f16x8 af[4][4];
    const float* fbase = feats + (size_t)blk * MB * DD;
    #pragma unroll
    for (int t = 0; t < 4; ++t) {
        const float* rp = fbase + (wv * 64 + t * 16 + rl) * DD + q * 8;
        #pragma unroll
        for (int kk = 0; kk < 4; ++kk) {
            float4 v0 = *(const float4*)(rp + kk * 32);
            float4 v1 = *(const float4*)(rp + kk * 32 + 4);
            f16x8 a;
            a[0] = (_Float16)v0.x; a[1] = (_Float16)v0.y;
            a[2] = (_Float16)v0.z; a[3] = (_Float16)v0.w;
            a[4] = (_Float16)v1.x; a[5] = (_Float16)v1.y;
            a[6] = (_Float16)v1.z; a[7] = (_Float16)v1.w;
            af[t][kk] = a;
        }
    }
    __syncthreads();                // B staged (vmcnt drained by barrier)

    float sp[4][4] = {{0,0,0,0},{0,0,0,0},{0,0,0,0},{0,0,0,0}};
    const int brow = rl << 8;
    const int bswz = (rl & 7) << 4;
    const int bq   = q << 4;        // q*8 elems = q*16 bytes

    for (int chunk = 0; chunk < 16; ++chunk) {
        const float bbv = b1[chunk * 16 + rl];
        const float ww  = W2[chunk * 16 + rl];
        const char* cb = Bl + chunk * 4096;
        f32x4 acc0 = {0,0,0,0}, acc1 = {0,0,0,0}, acc2 = {0,0,0,0}, acc3 = {0,0,0,0};
        #pragma unroll
        for (int kk = 0; kk < 4; ++kk) {
            f16x8 bf = *(const f16x8*)(cb + (((brow + (kk << 6) + bq)) ^ bswz));
            acc0 = __builtin_amdgcn_mfma_f32_16x16x32_f16(af[0][kk], bf, acc0, 0, 0, 0);
            acc1 = __builtin_amdgcn_mfma_f32_16x16x32_f16(af[1][kk], bf, acc1, 0, 0, 0);
            acc2 = __builtin_amdgcn_mfma_f32_16x16x32_f16(af[2][kk], bf, acc2, 0, 0, 0);
            acc3 = __builtin_amdgcn_mfma_f32_16x16x32_f16(af[3][kk], bf, acc3, 0, 0, 0);
        }
        // fold relu + W2; D layout: col = lane&15 (= rl), row = q*4 + j
        #pragma unroll
        for (int j = 0; j < 4; ++j) {
            sp[0][j] += fmaxf(acc0[j] + bbv, 0.f) * ww;
            sp[1][j] += fmaxf(acc1[j] + bbv, 0.f) * ww;
            sp[2][j] += fmaxf(acc2[j] + bbv, 0.f) * ww;
            sp[3][j] += fmaxf(acc3[j] + bbv, 0.f) * ww;
        }
    }

    // sum over the 16 cols (rl) held by each 16-lane group
    #pragma unroll
    for (int m = 1; m < 16; m <<= 1) {
        #pragma unroll
        for (int t = 0; t < 4; ++t)
            #pragma unroll
            for (int j = 0; j < 4; ++j)
                sp[t][j] += __shfl_xor(sp[t][j], m);
    }
    if (rl == 0) {
        float* so = scores + blk * MB + wv * 64;
        #pragma unroll
        for (int t = 0; t < 4; ++t)
            #pragma unroll
            for (int j = 0; j < 4; ++j)
                so[t * 16 + q * 4 + j] = sp[t][j];
    }
}

// ---------------------------------------------------------------------------
// K2: per-batch max and 1/sum(exp) over N scores
// ---------------------------------------------------------------------------
__global__ __launch_bounds__(256) void k_stats(const float* __restrict__ scores,
                                               float* __restrict__ mz) {
    const int b = blockIdx.x, tid = threadIdx.x;
    float s[16];
    #pragma unroll
    for (int k = 0; k < 16; ++k) s[k] = scores[b * NN + k * 256 + tid];

    float m = -1e30f;
    #pragma unroll
    for (int k = 0; k < 16; ++k) m = fmaxf(m, s[k]);
    #pragma unroll
    for (int o = 1; o < 64; o <<= 1) m = fmaxf(m, __shfl_xor(m, o));

    __shared__ float redm[4], redz[4];
    const int wv = tid >> 6, lane = tid & 63;
    if (lane == 0) redm[wv] = m;
    __syncthreads();
    m = fmaxf(fmaxf(redm[0], redm[1]), fmaxf(redm[2], redm[3]));

    float z = 0.f;
    #pragma unroll
    for (int k = 0; k < 16; ++k) z += expf(s[k] - m);
    #pragma unroll
    for (int o = 1; o < 64; o <<= 1) z += __shfl_xor(z, o);
    if (lane == 0) redz[wv] = z;
    __syncthreads();
    if (tid == 0) {
        z = redz[0] + redz[1] + redz[2] + redz[3];
        mz[b * 2]     = m;
        mz[b * 2 + 1] = 1.0f / z;
    }
}

// ---------------------------------------------------------------------------
// K3: partial weighted sums. block = (b, chunk of 256 nodes).
// ---------------------------------------------------------------------------
__global__ __launch_bounds__(256) void k_wsum(const float* __restrict__ feats,
                                              const float* __restrict__ scores,
                                              const float* __restrict__ mz,
                                              float* __restrict__ partials) {
    const int blk = blockIdx.x;
    const int b = blk >> 4, ch = blk & 15;
    const int tid = threadIdx.x;
    const int n0 = ch * 256;

    __shared__ float  wsm[256];
    __shared__ float4 accl[256];

    const float m  = mz[b * 2];
    const float iz = mz[b * 2 + 1];
    wsm[tid] = expf(scores[b * NN + n0 + tid] - m) * iz;
    __syncthreads();

    const int d4 = tid & 31;
    const int part = tid >> 5;
    const float4* fg4 = (const float4*)feats;
    const int base4 = (b * NN + n0 + part * 32) * 32;

    float4 acc = {0, 0, 0, 0};
    #pragma unroll 8
    for (int k = 0; k < 32; ++k) {
        const float w = wsm[part * 32 + k];
        const float4 f = fg4[base4 + k * 32 + d4];
        acc.x = fmaf(w, f.x, acc.x);
        acc.y = fmaf(w, f.y, acc.y);
        acc.z = fmaf(w, f.z, acc.z);
        acc.w = fmaf(w, f.w, acc.w);
    }
    accl[tid] = acc;
    __syncthreads();
    if (tid < 32) {
        float4 s = accl[tid];
        #pragma unroll
        for (int p = 1; p < 8; ++p) {
            float4 t = accl[p * 32 + tid];
            s.x += t.x; s.y += t.y; s.z += t.z; s.w += t.w;
        }
        ((float4*)partials)[blk * 32 + tid] = s;
    }
}

// ---------------------------------------------------------------------------
// K4: fold 16 chunk partials -> out[b,d]
// ---------------------------------------------------------------------------
__global__ __launch_bounds__(256) void k_final(const float* __restrict__ partials,
                                               float* __restrict__ out) {
    const int t = blockIdx.x * 256 + threadIdx.x;   // 0..8191
    const int b = t >> 7, d = t & 127;
    float s = 0.f;
    #pragma unroll
    for (int ch = 0; ch < 16; ++ch) s += partials[((b * 16 + ch) << 7) + d];
    out[t] = s;
}

extern "C" void kernel_launch(void* const* d_in, const int* in_sizes, int n_in,
                              void* d_out, int out_size, void* d_ws, size_t ws_size,
                              hipStream_t stream) {
    const float* feats = (const float*)d_in[0];
    const float* W1    = (const float*)d_in[1];
    const float* b1    = (const float*)d_in[2];
    const float* W2    = (const float*)d_in[3];
    // d_in[4] = b2: constant shift before softmax -> no effect on output.
    float* out = (float*)d_out;

    float* ws       = (float*)d_ws;
    float* scores   = ws;                       // 262144 floats
    float* mz       = ws + 262144;              // 128 floats
    float* partials = ws + 262144 + 128;        // 131072 floats
    char*  Bws      = (char*)d_ws + 1573376;    // 64 KiB: W1t fp16, swizzled

    hipLaunchKernelGGL(k_prep, dim3(DD), dim3(HH), 0, stream, W1, Bws);
    hipLaunchKernelGGL(k_scores, dim3(BB * NN / MB), dim3(256), 0, stream,
                       feats, Bws, b1, W2, scores);
    hipLaunchKernelGGL(k_stats, dim3(BB), dim3(256), 0, stream, scores, mz);
    hipLaunchKernelGGL(k_wsum, dim3(BB * 16), dim3(256), 0, stream,
                       feats, scores, mz, partials);
    hipLaunchKernelGGL(k_final, dim3(32), dim3(256), 0, stream, partials, out);
}

// Round 6
// 54.451 us; speedup vs baseline: 4.8624x; 1.2786x over previous
//
#include <hip/hip_runtime.h>
#include <math.h>

#define BB 64
#define NN 4096
#define DD 128
#define HH 256
#define MB 256                  // rows per fused block (4 waves x 4 tiles of 16)
#define NBLK (BB * NN / MB)     // 1024 blocks, 16 per batch
#define PSTRIDE 132             // per-block partial: 128 acc + m + z (+pad)

typedef __attribute__((ext_vector_type(8))) _Float16 f16x8;
typedef __attribute__((ext_vector_type(4))) float f32x4;

static __device__ __forceinline__ void gload_lds16(const void* g, void* l) {
    __builtin_amdgcn_global_load_lds(
        (const __attribute__((address_space(1))) unsigned int*)g,
        (__attribute__((address_space(3))) unsigned int*)l, 16, 0, 0);
}

// ---------------------------------------------------------------------------
// k_prep: W1 [128][256] fp32 -> Bws fp16, transposed per 16-col chunk,
// XOR-swizzled exactly as it will sit in LDS (linear global_load_lds copy).
// chunk region = 4096 B; elem (cl, k) at ((cl<<8)+(k<<1)) ^ ((cl&7)<<4).
// ---------------------------------------------------------------------------
__global__ __launch_bounds__(256) void k_prep(const float* __restrict__ W1,
                                              char* __restrict__ Bws) {
    const int k = blockIdx.x;       // 0..127
    const int c = threadIdx.x;      // 0..255
    const _Float16 h = (_Float16)W1[k * HH + c];
    const int chunk = c >> 4, cl = c & 15;
    const int off = ((cl << 8) + (k << 1)) ^ ((cl & 7) << 4);
    *(_Float16*)(Bws + chunk * 4096 + off) = h;
}

// ---------------------------------------------------------------------------
// k_fused: per block of 256 rows:
//   scores -> local softmax (m_blk, e_i, z_blk) -> weighted partial from the
//   SAME fp16 A fragments already in registers. One pass over feats.
// Partials recombined exactly by k_out (flash-style rescale).
// ---------------------------------------------------------------------------
__global__ __launch_bounds__(256, 2) void k_fused(const float* __restrict__ feats,
                                                  const char* __restrict__ Bws,
                                                  const float* __restrict__ b1,
                                                  const float* __restrict__ W2,
                                                  float* __restrict__ parts) {
    __shared__ char  Bl[65536];     // 16 chunks x 16 cols x 128 k, fp16 swizzled
    __shared__ float scores_l[256];
    __shared__ float ew[256];
    __shared__ float wacc[4][128];
    __shared__ float redm[4], redz[4];

    const int tid  = threadIdx.x;
    const int lane = tid & 63;
    const int wv   = tid >> 6;
    const int blk  = blockIdx.x;
    const int rl   = lane & 15;     // A row within tile / B col within chunk
    const int q    = lane >> 4;     // k-quarter (8 elems per K=32 step)

    // ---- stage all of B: 64 KiB = 16 iters x 256 threads x 16 B (linear)
    #pragma unroll
    for (int it = 0; it < 16; ++it)
        gload_lds16(Bws + it * 4096 + tid * 16, Bl + it * 4096 + tid * 16);

    // ---- A fragments direct from global, fp32->fp16 in regs.
    // lane (q,rl) holds rows r(t)=wv*64+t*16+rl, k = kk*32 + q*8 + e.
    f16x8 af[4][4];
    const float* fbase = feats + (size_t)blk * MB * DD;
    #pragma unroll
    for (int t = 0; t < 4; ++t) {
        const float* rp = fbase + (wv * 64 + t * 16 + rl) * DD + q * 8;
        #pragma unroll
        for (int kk = 0; kk < 4; ++kk) {
            float4 v0 = *(const float4*)(rp + kk * 32);
            float4 v1 = *(const float4*)(rp + kk * 32 + 4);
            f16x8 a;
            a[0] = (_Float16)v0.x; a[1] = (_Float16)v0.y;
            a[2] = (_Float16)v0.z; a[3] = (_Float16)v0.w;
            a[4] = (_Float16)v1.x; a[5] = (_Float16)v1.y;
            a[6] = (_Float16)v1.z; a[7] = (_Float16)v1.w;
            af[t][kk] = a;
        }
    }
    __syncthreads();                // B staged (vmcnt drained by barrier)

    float sp[4][4] = {{0,0,0,0},{0,0,0,0},{0,0,0,0},{0,0,0,0}};
    const int brow = rl << 8;
    const int bswz = (rl & 7) << 4;
    const int bq   = q << 4;

    for (int chunk = 0; chunk < 16; ++chunk) {
        const float bbv = b1[chunk * 16 + rl];
        const float ww  = W2[chunk * 16 + rl];
        const char* cb = Bl + chunk * 4096;
        f32x4 acc0 = {0,0,0,0}, acc1 = {0,0,0,0}, acc2 = {0,0,0,0}, acc3 = {0,0,0,0};
        #pragma unroll
        for (int kk = 0; kk < 4; ++kk) {
            f16x8 bf = *(const f16x8*)(cb + (((brow + (kk << 6) + bq)) ^ bswz));
            acc0 = __builtin_amdgcn_mfma_f32_16x16x32_f16(af[0][kk], bf, acc0, 0, 0, 0);
            acc1 = __builtin_amdgcn_mfma_f32_16x16x32_f16(af[1][kk], bf, acc1, 0, 0, 0);
            acc2 = __builtin_amdgcn_mfma_f32_16x16x32_f16(af[2][kk], bf, acc2, 0, 0, 0);
            acc3 = __builtin_amdgcn_mfma_f32_16x16x32_f16(af[3][kk], bf, acc3, 0, 0, 0);
        }
        // fold relu + W2; D layout: col = rl, row = q*4 + j (within tile t)
        #pragma unroll
        for (int j = 0; j < 4; ++j) {
            sp[0][j] += fmaxf(acc0[j] + bbv, 0.f) * ww;
            sp[1][j] += fmaxf(acc1[j] + bbv, 0.f) * ww;
            sp[2][j] += fmaxf(acc2[j] + bbv, 0.f) * ww;
            sp[3][j] += fmaxf(acc3[j] + bbv, 0.f) * ww;
        }
    }

    // ---- scores: reduce over the 16 col-lanes (rl), publish to LDS
    #pragma unroll
    for (int m = 1; m < 16; m <<= 1)
        #pragma unroll
        for (int t = 0; t < 4; ++t)
            #pragma unroll
            for (int j = 0; j < 4; ++j)
                sp[t][j] += __shfl_xor(sp[t][j], m);
    if (rl == 0) {
        #pragma unroll
        for (int t = 0; t < 4; ++t)
            #pragma unroll
            for (int j = 0; j < 4; ++j)
                scores_l[wv * 64 + t * 16 + q * 4 + j] = sp[t][j];
    }
    __syncthreads();

    // ---- block-local softmax stats over the 256 rows
    const float s = scores_l[tid];
    float mx = s;
    #pragma unroll
    for (int o = 1; o < 64; o <<= 1) mx = fmaxf(mx, __shfl_xor(mx, o));
    if (lane == 0) redm[wv] = mx;
    __syncthreads();
    mx = fmaxf(fmaxf(redm[0], redm[1]), fmaxf(redm[2], redm[3]));
    const float e = expf(s - mx);
    ew[tid] = e;
    float z = e;
    #pragma unroll
    for (int o = 1; o < 64; o <<= 1) z += __shfl_xor(z, o);
    if (lane == 0) redz[wv] = z;
    __syncthreads();
    const float zblk = redz[0] + redz[1] + redz[2] + redz[3];

    // ---- weighted partial sum from the A fragments in registers
    const float w0 = ew[wv * 64 +  0 + rl];
    const float w1 = ew[wv * 64 + 16 + rl];
    const float w2 = ew[wv * 64 + 32 + rl];
    const float w3 = ew[wv * 64 + 48 + rl];
    float acc[4][8];
    #pragma unroll
    for (int kk = 0; kk < 4; ++kk)
        #pragma unroll
        for (int e8 = 0; e8 < 8; ++e8)
            acc[kk][e8] = w0 * (float)af[0][kk][e8] + w1 * (float)af[1][kk][e8]
                        + w2 * (float)af[2][kk][e8] + w3 * (float)af[3][kk][e8];
    // reduce over the 16 row-lanes (rl) holding the same k-slice
    #pragma unroll
    for (int m = 1; m < 16; m <<= 1)
        #pragma unroll
        for (int kk = 0; kk < 4; ++kk)
            #pragma unroll
            for (int e8 = 0; e8 < 8; ++e8)
                acc[kk][e8] += __shfl_xor(acc[kk][e8], m);
    if (rl == 0) {
        #pragma unroll
        for (int kk = 0; kk < 4; ++kk)
            #pragma unroll
            for (int e8 = 0; e8 < 8; ++e8)
                wacc[wv][kk * 32 + q * 8 + e8] = acc[kk][e8];
    }
    __syncthreads();

    // ---- fold 4 waves, emit per-block partial (128 acc + m + z)
    if (tid < 128) {
        float p = wacc[0][tid] + wacc[1][tid] + wacc[2][tid] + wacc[3][tid];
        parts[blk * PSTRIDE + tid] = p;
    } else if (tid == 128) {
        parts[blk * PSTRIDE + 128] = mx;
        parts[blk * PSTRIDE + 129] = zblk;
    }
}

// ---------------------------------------------------------------------------
// k_out: combine 16 block-partials per batch with exact softmax rescaling.
// ---------------------------------------------------------------------------
__global__ __launch_bounds__(128) void k_out(const float* __restrict__ parts,
                                             float* __restrict__ out) {
    const int b = blockIdx.x;       // 0..63
    const int d = threadIdx.x;      // 0..127
    const float* pb = parts + (size_t)b * 16 * PSTRIDE;
    float M = -1e30f;
    #pragma unroll
    for (int i = 0; i < 16; ++i) M = fmaxf(M, pb[i * PSTRIDE + 128]);
    float num = 0.f, den = 0.f;
    #pragma unroll
    for (int i = 0; i < 16; ++i) {
        const float sc = expf(pb[i * PSTRIDE + 128] - M);
        num = fmaf(sc, pb[i * PSTRIDE + d], num);
        den = fmaf(sc, pb[i * PSTRIDE + 129], den);
    }
    out[b * DD + d] = num / den;
}

extern "C" void kernel_launch(void* const* d_in, const int* in_sizes, int n_in,
                              void* d_out, int out_size, void* d_ws, size_t ws_size,
                              hipStream_t stream) {
    const float* feats = (const float*)d_in[0];
    const float* W1    = (const float*)d_in[1];
    const float* b1    = (const float*)d_in[2];
    const float* W2    = (const float*)d_in[3];
    // d_in[4] = b2: constant shift before softmax -> no effect on output.
    float* out = (float*)d_out;

    char*  Bws   = (char*)d_ws;                     // 64 KiB: W1t fp16 swizzled
    float* parts = (float*)((char*)d_ws + 65536);   // 1024 * 132 floats

    hipLaunchKernelGGL(k_prep, dim3(DD), dim3(HH), 0, stream, W1, Bws);
    hipLaunchKernelGGL(k_fused, dim3(NBLK), dim3(256), 0, stream,
                       feats, Bws, b1, W2, parts);
    hipLaunchKernelGGL(k_out, dim3(BB), dim3(128), 0, stream, parts, out);
}